// Round 6
// baseline (252.701 us; speedup 1.0000x reference)
//
#include <hip/hip_runtime.h>
#include <math.h>

// Problem constants: B=32, E=1024, H=1024, N=128, L=64, K=8
#define NB 32
#define NE 1024
#define NH 1024
#define NN 128
#define NL 64
#define NK 8
#define GS 8     // g-chunks for qk partial sums
#define NBLK 256 // persistent blocks (1 per CU; capacity-safe residency)
#define BS 512   // threads per block (8 waves)

// Barrier state in device globals: zero-initialized at module load, never
// poisoned by the harness (it poisons only d_out/d_ws), and self-reset to 0
// at the end of every call -> deterministic across graph replays, no memset.
__device__ int g_flags[4][NBLK];
__device__ int g_gen[4];
__device__ int g_cntb[NB];

__device__ __forceinline__ float dot4f(float4 a, float4 b) {
    return a.x * b.x + a.y * b.y + a.z * b.z + a.w * b.w;
}

// ---------------------------------------------------------------------------
// Flag-array grid barrier (no arrival RMW contention):
//  worker block: release-store own flag; spin-read gen (read-only broadcast).
//  block 0: 255 threads poll distinct flags in parallel, reset them, then one
//  release-store of gen. gen[K-1] is reset at barrier K (provably safe: every
//  flags[K] set implies every block passed gen[K-1]).
// ---------------------------------------------------------------------------
__device__ __forceinline__ void mega_barrier(int K) {
    __syncthreads();
    if (blockIdx.x == 0) {
        int t = threadIdx.x;
        if (t > 0 && t < NBLK) {
            while (__hip_atomic_load(&g_flags[K][t], __ATOMIC_ACQUIRE,
                                     __HIP_MEMORY_SCOPE_AGENT) == 0)
                __builtin_amdgcn_s_sleep(1);
            __hip_atomic_store(&g_flags[K][t], 0, __ATOMIC_RELAXED,
                               __HIP_MEMORY_SCOPE_AGENT);
        }
        __syncthreads();
        if (t == 0) {
            __threadfence();
            if (K > 0)
                __hip_atomic_store(&g_gen[K - 1], 0, __ATOMIC_RELAXED,
                                   __HIP_MEMORY_SCOPE_AGENT);
            __hip_atomic_store(&g_gen[K], 1, __ATOMIC_RELEASE,
                               __HIP_MEMORY_SCOPE_AGENT);
        }
        __syncthreads();
    } else {
        if (threadIdx.x == 0) {
            __threadfence();
            __hip_atomic_store(&g_flags[K][blockIdx.x], 1, __ATOMIC_RELEASE,
                               __HIP_MEMORY_SCOPE_AGENT);
            while (__hip_atomic_load(&g_gen[K], __ATOMIC_ACQUIRE,
                                     __HIP_MEMORY_SCOPE_AGENT) == 0)
                __builtin_amdgcn_s_sleep(1);
            __threadfence();
        }
        __syncthreads();
    }
}

// Final arrival-only round: workers just flag and exit; block 0 collects,
// resets everything (incl. gen[2]) so all device-global state returns to 0.
__device__ __forceinline__ void mega_finish() {
    __syncthreads();
    if (blockIdx.x == 0) {
        int t = threadIdx.x;
        if (t > 0 && t < NBLK) {
            while (__hip_atomic_load(&g_flags[3][t], __ATOMIC_ACQUIRE,
                                     __HIP_MEMORY_SCOPE_AGENT) == 0)
                __builtin_amdgcn_s_sleep(1);
            __hip_atomic_store(&g_flags[3][t], 0, __ATOMIC_RELAXED,
                               __HIP_MEMORY_SCOPE_AGENT);
        }
        __syncthreads();
        if (t == 0)
            __hip_atomic_store(&g_gen[2], 0, __ATOMIC_RELAXED,
                               __HIP_MEMORY_SCOPE_AGENT);
    } else if (threadIdx.x == 0) {
        __hip_atomic_store(&g_flags[3][blockIdx.x], 1, __ATOMIC_RELEASE,
                           __HIP_MEMORY_SCOPE_AGENT);
    }
}

// ---------------------------------------------------------------------------
// rowdot8: one wave computes dot(W[o,:], A[b,:]) + bias[o] for 8 consecutive b
// ---------------------------------------------------------------------------
template <int D>
__device__ void rowdot8(const float* __restrict__ A, const float* __restrict__ W,
                        const float* __restrict__ bias, float* __restrict__ C,
                        int wid) {
    int lane = threadIdx.x & 63;
    int o  = wid >> 2;          // 0..1023
    int b0 = (wid & 3) * 8;     // batch group of 8
    const float4* Wr = (const float4*)(W + (size_t)o * D);
    const float4* Ar[8];
#pragma unroll
    for (int i = 0; i < 8; ++i) Ar[i] = (const float4*)(A + (size_t)(b0 + i) * D);
    float acc[8] = {0.f, 0.f, 0.f, 0.f, 0.f, 0.f, 0.f, 0.f};
#pragma unroll
    for (int c = 0; c < D / 256; ++c) {
        float4 w4 = Wr[c * 64 + lane];
#pragma unroll
        for (int i = 0; i < 8; ++i) acc[i] += dot4f(w4, Ar[i][c * 64 + lane]);
    }
#pragma unroll
    for (int s = 32; s; s >>= 1)
#pragma unroll
        for (int i = 0; i < 8; ++i) acc[i] += __shfl_down(acc[i], s, 64);
    if (lane == 0) {
        float bb = bias[o];
#pragma unroll
        for (int i = 0; i < 8; ++i) C[(size_t)(b0 + i) * NH + o] = acc[i] + bb;
    }
}

// ---------------------------------------------------------------------------
// MEGA: all stages in one kernel; 3 flag barriers + 1 arrival-only round.
// ---------------------------------------------------------------------------
__global__ __launch_bounds__(BS)
void mega_kernel(const float* __restrict__ inputs,
                 const float* __restrict__ Wq,  const float* __restrict__ bq,
                 const float* __restrict__ Wk,
                 const float* __restrict__ Wc,  const float* __restrict__ bc,
                 const float* __restrict__ cache_keys,
                 const float* __restrict__ cache_values,
                 float* __restrict__ out,
                 float* __restrict__ scores, float* __restrict__ query,
                 float* __restrict__ pqk,    float* __restrict__ patt,
                 float* __restrict__ F,      float* __restrict__ weights,
                 int* __restrict__ top_idx) {
    __shared__ float qlds[2][1024];   // 8KB  (P2, per half-block)
    __shared__ float red[2][2048];    // 16KB (P2)
    __shared__ float qk_lds[NH];      // 4KB  (P3)
    __shared__ float logits_s[NL];
    __shared__ float coef_s[NL];
    __shared__ float psum[2][NH];     // 8KB  (P3)
    __shared__ int last_s;

    int t = threadIdx.x, bid = blockIdx.x;
    int lane = t & 63;
    int gw = bid * 8 + (t >> 6);      // global wave id, 0..2047

    // ---- P1: scores (4096 wave-units) + query rowdot (4096 wave-units) ----
    for (int u = gw; u < 8192; u += 2048) {
        if (u < 4096) {
            int b = u >> 7, n = u & 127;
            const float4* ck = (const float4*)(cache_keys + ((size_t)b * NN + n) * NE);
            const float4* in = (const float4*)(inputs + (size_t)b * NE);
            float acc = 0.f;
#pragma unroll
            for (int c = 0; c < 4; ++c) acc += dot4f(ck[c * 64 + lane], in[c * 64 + lane]);
#pragma unroll
            for (int s = 32; s; s >>= 1) acc += __shfl_down(acc, s, 64);
            if (lane == 0) scores[b * NN + n] = acc;
        } else {
            rowdot8<1024>(inputs, Wq, bq, query, u - 4096);
        }
    }
    mega_barrier(0);

    // ---- P2: pqk tiles (1024 units) + topk (32 units), half-block units ----
    // pqk[gs][b][h] = sum_{g in chunk of 128} query[b,g]*Wk[g,h]
    // (bk dropped: q·bk constant over l -> cancels in the l-softmax)
    {
        int hb = t >> 8, tt = t & 255;
        for (int i = 0; i < 3; ++i) {
            int u = bid * 2 + hb + i * 512;
            bool pq = (u < 1024);
            int gs = u & 7, hs = (u >> 3) & 31, bg = u >> 8, b0 = bg * 8;
            if (pq) {
#pragma unroll
                for (int j = 0; j < 4; ++j) {
                    int idx = tt * 4 + j;
                    int g = idx >> 3, bj = idx & 7;
                    qlds[hb][idx] = query[(size_t)(b0 + bj) * NH + gs * 128 + g];
                }
            }
            __syncthreads();
            if (pq) {
                int h_local = tt & 31, g_lane = tt >> 5;
                int h = hs * 32 + h_local;
                float acc[8] = {0.f, 0.f, 0.f, 0.f, 0.f, 0.f, 0.f, 0.f};
#pragma unroll
                for (int ii = 0; ii < 16; ++ii) {
                    int g_local = g_lane * 16 + ii;
                    float w = Wk[(size_t)(gs * 128 + g_local) * NH + h];
                    float4 q0 = *(const float4*)&qlds[hb][g_local * 8];
                    float4 q1 = *(const float4*)&qlds[hb][g_local * 8 + 4];
                    acc[0] += q0.x * w; acc[1] += q0.y * w;
                    acc[2] += q0.z * w; acc[3] += q0.w * w;
                    acc[4] += q1.x * w; acc[5] += q1.y * w;
                    acc[6] += q1.z * w; acc[7] += q1.w * w;
                }
                *(float4*)&red[hb][(g_lane * 32 + h_local) * 8]     = *(float4*)&acc[0];
                *(float4*)&red[hb][(g_lane * 32 + h_local) * 8 + 4] = *(float4*)&acc[4];
            } else if (u < 1056 && tt < 64) {
                // register-only topk: butterfly leaves winner in every lane
                int b = u - 1024;
                float s0 = scores[b * NN + tt];
                float s1 = scores[b * NN + 64 + tt];
                float tvr[NK]; int tir[NK];
#pragma unroll
                for (int kk = 0; kk < NK; ++kk) {
                    float v = s0; int idx = tt;
                    if (s1 > v) { v = s1; idx = tt + 64; }
#pragma unroll
                    for (int s = 1; s < 64; s <<= 1) {
                        float ov = __shfl_xor(v, s, 64);
                        int   oi = __shfl_xor(idx, s, 64);
                        if (ov > v || (ov == v && oi < idx)) { v = ov; idx = oi; }
                    }
                    tvr[kk] = v; tir[kk] = idx;
                    if (idx == tt)      s0 = -INFINITY;
                    if (idx == tt + 64) s1 = -INFINITY;
                }
                if (tt == 0) {
                    float sum = 0.f;
#pragma unroll
                    for (int kk = 0; kk < NK; ++kk) sum += __expf(tvr[kk] - tvr[0]);
#pragma unroll
                    for (int kk = 0; kk < NK; ++kk) {
                        weights[b * NK + kk] = __expf(tvr[kk] - tvr[0]) / sum;
                        top_idx[b * NK + kk] = tir[kk];
                    }
                }
            }
            __syncthreads();
            if (pq) {
                int bj = tt >> 5, hl = tt & 31;
                float ssum = 0.f;
#pragma unroll
                for (int gl = 0; gl < 8; ++gl) ssum += red[hb][(gl * 32 + hl) * 8 + bj];
                pqk[((size_t)gs * NB + b0 + bj) * NH + hs * 32 + hl] = ssum;
            }
        }
    }
    mega_barrier(1);

    // ---- P3: attention, one (b,k) per block, 8 waves; last block per b
    //      assembles F (per-b 8-contender counter, self-resetting) ----
    {
        int b = bid >> 3, k = bid & 7;
        if (t < 256) {
            float4 s = make_float4(0.f, 0.f, 0.f, 0.f);
#pragma unroll
            for (int gs = 0; gs < GS; ++gs) {
                float4 p = ((const float4*)pqk)[((size_t)gs * NB + b) * 256 + t];
                s.x += p.x; s.y += p.y; s.z += p.z; s.w += p.w;
            }
            ((float4*)qk_lds)[t] = s;
        }
        __syncthreads();

        int wv = t >> 6;
        int zi = top_idx[b * NK + k];
        const float* zbase = cache_values + (((size_t)b * NN + zi) * NL) * NH;

        // logits: 8 waves x 8 rows
        {
            float4 qk[4];
#pragma unroll
            for (int c = 0; c < 4; ++c) qk[c] = ((const float4*)qk_lds)[c * 64 + lane];
            for (int r = 0; r < 8; ++r) {
                int l = wv * 8 + r;
                const float4* zr = (const float4*)(zbase + (size_t)l * NH);
                float dot = 0.f;
#pragma unroll
                for (int c = 0; c < 4; ++c) dot += dot4f(zr[c * 64 + lane], qk[c]);
#pragma unroll
                for (int s = 32; s; s >>= 1) dot += __shfl_down(dot, s, 64);
                if (lane == 0) logits_s[l] = dot * 0.03125f;   // 1/sqrt(1024)
            }
        }
        __syncthreads();
        // softmax over l, retrieval weight folded
        if (t < 64) {
            float v = logits_s[t];
            float m = v;
#pragma unroll
            for (int s = 1; s < 64; s <<= 1) m = fmaxf(m, __shfl_xor(m, s, 64));
            float e = __expf(v - m);
            float sum = e;
#pragma unroll
            for (int s = 1; s < 64; s <<= 1) sum += __shfl_xor(sum, s, 64);
            coef_s[t] = weights[b * NK + k] * e / sum;
        }
        __syncthreads();
        // PV: group g (256 threads) sums rows [g*32, g*32+32)
        {
            int grp = t >> 8, tt = t & 255;
            float4 acc = make_float4(0.f, 0.f, 0.f, 0.f);
            for (int rr = 0; rr < 32; ++rr) {
                int l = grp * 32 + rr;
                float c = coef_s[l];
                float4 z = ((const float4*)(zbase + (size_t)l * NH))[tt];
                acc.x += c * z.x; acc.y += c * z.y; acc.z += c * z.z; acc.w += c * z.w;
            }
            ((float4*)psum[grp])[tt] = acc;
        }
        __syncthreads();
        if (t < 256) {
            float4 a = ((const float4*)psum[0])[t];
            float4 b4 = ((const float4*)psum[1])[t];
            a.x += b4.x; a.y += b4.y; a.z += b4.z; a.w += b4.w;
            ((float4*)patt)[((size_t)b * NK + k) * 256 + t] = a;
        }
        // F assembly by the last-arriving block for this b
        __threadfence();
        __syncthreads();
        if (t == 0)
            last_s = __hip_atomic_fetch_add(&g_cntb[b], 1, __ATOMIC_ACQ_REL,
                                            __HIP_MEMORY_SCOPE_AGENT);
        __syncthreads();
        if (last_s == NK - 1) {
            __threadfence();   // acquire side: other blocks' patt visible
            int j4 = t;        // 512 threads == 512 float4 == one F row
            float4 v;
            if (j4 < 256) {
                v = make_float4(0.f, 0.f, 0.f, 0.f);
#pragma unroll
                for (int kk = 0; kk < NK; ++kk) {
                    float4 p = ((const float4*)patt)[((size_t)b * NK + kk) * 256 + j4];
                    v.x += p.x; v.y += p.y; v.z += p.z; v.w += p.w;
                }
            } else {
                v = ((const float4*)(inputs + (size_t)b * NE))[j4 - 256];
            }
            ((float4*)F)[(size_t)b * 512 + j4] = v;
            if (t == 0)
                __hip_atomic_store(&g_cntb[b], 0, __ATOMIC_RELAXED,
                                   __HIP_MEMORY_SCOPE_AGENT);   // self-reset
        }
    }
    mega_barrier(2);

    // ---- P5: out = F @ Wc^T + bc (4096 wave-units) ----
    for (int u = gw; u < 4096; u += 2048)
        rowdot8<2048>(F, Wc, bc, out, u);

    mega_finish();
}

// ---------------------------------------------------------------------------
extern "C" void kernel_launch(void* const* d_in, const int* in_sizes, int n_in,
                              void* d_out, int out_size, void* d_ws, size_t ws_size,
                              hipStream_t stream) {
    const float* inputs       = (const float*)d_in[0];
    const float* Wq           = (const float*)d_in[1];
    const float* bq           = (const float*)d_in[2];
    const float* Wk           = (const float*)d_in[3];
    // d_in[4] = bk: cancels in the l-softmax (constant over l)
    const float* Wc           = (const float*)d_in[5];
    const float* bc           = (const float*)d_in[6];
    const float* cache_keys   = (const float*)d_in[7];
    const float* cache_values = (const float*)d_in[8];
    float* out = (float*)d_out;

    float* ws      = (float*)d_ws;
    float* scores  = ws;                       // 4096
    float* query   = scores + 4096;            // 32768
    float* pqk     = query + 32768;            // 8*32*1024 = 262144
    float* patt    = pqk + 262144;             // 32*8*1024 = 262144
    float* F       = patt + 262144;            // 65536
    float* weights = F + 65536;                // 256
    int*   tidx    = (int*)(weights + 256);    // 256 ints
    (void)ws_size; (void)n_in; (void)in_sizes; (void)out_size;

    mega_kernel<<<NBLK, BS, 0, stream>>>(inputs, Wq, bq, Wk, Wc, bc,
                                         cache_keys, cache_values, out,
                                         scores, query, pqk, patt, F,
                                         weights, tidx);
}

// Round 7
// 114.144 us; speedup vs baseline: 2.2139x; 2.2139x over previous
//
#include <hip/hip_runtime.h>
#include <math.h>

// Problem constants: B=32, E=1024, H=1024, N=128, L=64, K=8
#define NB 32
#define NE 1024
#define NH 1024
#define NN 128
#define NL 64
#define NK 8
#define GS 8   // g-chunks for qk partial sums

// Per-batch completion counter for in-kernel F assembly.
// Device global: zero at module load, self-reset after each use ->
// deterministic across graph replays, never touched by harness poisoning.
__device__ int g_cntb[NB];

__device__ __forceinline__ float dot4f(float4 a, float4 b) {
    return a.x * b.x + a.y * b.y + a.z * b.z + a.w * b.w;
}

// ---------------------------------------------------------------------------
// rowdot8: one wave computes dot(W[o,:], A[b,:]) + bias[o] for 8 consecutive b
// ---------------------------------------------------------------------------
template <int D>
__device__ void rowdot8(const float* __restrict__ A, const float* __restrict__ W,
                        const float* __restrict__ bias, float* __restrict__ C,
                        int wid) {
    int lane = threadIdx.x & 63;
    int o  = wid >> 2;          // 0..1023
    int b0 = (wid & 3) * 8;     // batch group of 8
    const float4* Wr = (const float4*)(W + (size_t)o * D);
    const float4* Ar[8];
#pragma unroll
    for (int i = 0; i < 8; ++i) Ar[i] = (const float4*)(A + (size_t)(b0 + i) * D);
    float acc[8] = {0.f, 0.f, 0.f, 0.f, 0.f, 0.f, 0.f, 0.f};
#pragma unroll
    for (int c = 0; c < D / 256; ++c) {
        float4 w4 = Wr[c * 64 + lane];
#pragma unroll
        for (int i = 0; i < 8; ++i) acc[i] += dot4f(w4, Ar[i][c * 64 + lane]);
    }
#pragma unroll
    for (int s = 32; s; s >>= 1)
#pragma unroll
        for (int i = 0; i < 8; ++i) acc[i] += __shfl_down(acc[i], s, 64);
    if (lane == 0) {
        float bb = bias[o];
#pragma unroll
        for (int i = 0; i < 8; ++i) C[(size_t)(b0 + i) * NH + o] = acc[i] + bb;
    }
}

// ---------------------------------------------------------------------------
// FAT1: blocks [0,1024): scores[b,n] = cache_keys[b,n,:]·inputs[b,:]
//       blocks [1024,2048): query = inputs @ Wq^T + bq
// ---------------------------------------------------------------------------
__global__ __launch_bounds__(256)
void fat1_kernel(const float* __restrict__ cache_keys,
                 const float* __restrict__ inputs,
                 const float* __restrict__ Wq,
                 const float* __restrict__ bq,
                 float* __restrict__ scores,
                 float* __restrict__ query) {
    if (blockIdx.x < 1024) {
        int wid  = blockIdx.x * 4 + (threadIdx.x >> 6);   // 0..4095
        int lane = threadIdx.x & 63;
        int b = wid >> 7, n = wid & 127;
        const float4* ck = (const float4*)(cache_keys + ((size_t)b * NN + n) * NE);
        const float4* in = (const float4*)(inputs + (size_t)b * NE);
        float acc = 0.f;
#pragma unroll
        for (int c = 0; c < 4; ++c) acc += dot4f(ck[c * 64 + lane], in[c * 64 + lane]);
#pragma unroll
        for (int s = 32; s; s >>= 1) acc += __shfl_down(acc, s, 64);
        if (lane == 0) scores[b * NN + n] = acc;
    } else {
        int wid = (blockIdx.x - 1024) * 4 + (threadIdx.x >> 6);  // 0..4095
        rowdot8<1024>(inputs, Wq, bq, query, wid);
    }
}

// ---------------------------------------------------------------------------
// FAT2: blocks [0,1024): pqk partial GEMM tiled (16KB Wk per block);
//       blocks [1024,1056): per-batch top-8 + softmax.
// pqk[gs][b][h] = sum_{g in gs-chunk of 128} query[b,g] * Wk[g,h]
// (bk dropped: q·bk constant over l -> cancels in the l-softmax)
// ---------------------------------------------------------------------------
__global__ __launch_bounds__(256)
void fat2_kernel(const float* __restrict__ query,
                 const float* __restrict__ Wk,
                 const float* __restrict__ scores,
                 float* __restrict__ pqk,
                 int* __restrict__ top_idx,
                 float* __restrict__ weights) {
    __shared__ float qlds[128 * 8];     // [g_local][bj]  4KB
    __shared__ float red[8 * 32 * 8];   // [g_lane][h_local][bj] 8KB
    __shared__ float tv[NK];
    int t = threadIdx.x;
    if (blockIdx.x < 1024) {
        int gs = blockIdx.x & 7;
        int hs = (blockIdx.x >> 3) & 31;
        int bg = blockIdx.x >> 8;
        int b0 = bg * 8;
#pragma unroll
        for (int j = 0; j < 4; ++j) {
            int idx = t * 4 + j;
            int g = idx >> 3, bj = idx & 7;
            qlds[idx] = query[(size_t)(b0 + bj) * NH + gs * 128 + g];
        }
        __syncthreads();
        int h_local = t & 31, g_lane = t >> 5;
        int h = hs * 32 + h_local;
        float acc[8] = {0.f, 0.f, 0.f, 0.f, 0.f, 0.f, 0.f, 0.f};
#pragma unroll
        for (int i = 0; i < 16; ++i) {
            int g_local = g_lane * 16 + i;
            float w = Wk[(size_t)(gs * 128 + g_local) * NH + h];
            float4 q0 = *(const float4*)&qlds[g_local * 8];
            float4 q1 = *(const float4*)&qlds[g_local * 8 + 4];
            acc[0] += q0.x * w; acc[1] += q0.y * w; acc[2] += q0.z * w; acc[3] += q0.w * w;
            acc[4] += q1.x * w; acc[5] += q1.y * w; acc[6] += q1.z * w; acc[7] += q1.w * w;
        }
        *(float4*)&red[(g_lane * 32 + h_local) * 8]     = *(float4*)&acc[0];
        *(float4*)&red[(g_lane * 32 + h_local) * 8 + 4] = *(float4*)&acc[4];
        __syncthreads();
        int bj = t >> 5, hl = t & 31;
        float ssum = 0.f;
#pragma unroll
        for (int gl = 0; gl < 8; ++gl) ssum += red[(gl * 32 + hl) * 8 + bj];
        pqk[((size_t)gs * NB + b0 + bj) * NH + hs * 32 + hl] = ssum;
    } else {
        int b = blockIdx.x - 1024;
        if (t < 64) {
            float s0 = scores[b * NN + t];
            float s1 = scores[b * NN + 64 + t];
            for (int i = 0; i < NK; ++i) {
                float v = s0; int idx = t;
                if (s1 > v) { v = s1; idx = t + 64; }
#pragma unroll
                for (int s = 1; s < 64; s <<= 1) {
                    float ov = __shfl_xor(v, s, 64);
                    int   oi = __shfl_xor(idx, s, 64);
                    if (ov > v || (ov == v && oi < idx)) { v = ov; idx = oi; }
                }
                if (t == 0) { tv[i] = v; top_idx[b * NK + i] = idx; }
                if (idx == t)      s0 = -INFINITY;
                if (idx == t + 64) s1 = -INFINITY;
            }
        }
        __syncthreads();
        if (t < NK) {
            float e = __expf(tv[t] - tv[0]);   // tv[0] is the max
            float sum = e;
            sum += __shfl_xor(sum, 1, 64);
            sum += __shfl_xor(sum, 2, 64);
            sum += __shfl_xor(sum, 4, 64);
            weights[b * NK + t] = e / sum;
        }
    }
}

// ---------------------------------------------------------------------------
// ATTN3: one 512-thread block per (b,k). SINGLE pass over the zone:
// each of 8 waves streams 8 rows with per-wave online softmax (acc spans the
// full H via 16 floats/lane), hand-pipelined next-row prefetch; then 3-level
// LDS merge (8->4->2->1). Last-arriving block per b assembles F.
// ~80 VGPR, ~20KB LDS.
// ---------------------------------------------------------------------------
__global__ __launch_bounds__(512)
void attn3_kernel(const float* __restrict__ pqk,
                  const float* __restrict__ cache_values,
                  const int* __restrict__ top_idx,
                  const float* __restrict__ weights,
                  const float* __restrict__ inputs,
                  float* __restrict__ patt,
                  float* __restrict__ F) {
    int b = blockIdx.x >> 3, k = blockIdx.x & 7;
    __shared__ float qk_lds[NH];      // 4KB
    __shared__ float mbuf[4][NH];     // 16KB merge buffers
    __shared__ float md_lds[8][2];
    __shared__ int last_s;
    int t = threadIdx.x, lane = t & 63, wv = t >> 6;

    // qk[b,h] = sum_gs pqk[gs][b][h]; 512 threads cover 1024 h (2 each)
    {
        float s0 = 0.f, s1 = 0.f;
#pragma unroll
        for (int gs = 0; gs < GS; ++gs) {
            const float* p = pqk + ((size_t)gs * NB + b) * NH;
            s0 += p[t]; s1 += p[t + 512];
        }
        qk_lds[t] = s0; qk_lds[t + 512] = s1;
    }
    __syncthreads();

    float4 qk[4];
#pragma unroll
    for (int c = 0; c < 4; ++c) qk[c] = ((const float4*)qk_lds)[c * 64 + lane];

    int zi = top_idx[b * NK + k];
    const float* zbase = cache_values + (((size_t)b * NN + zi) * NL) * NH;

    float m = -INFINITY, d = 0.f;
    float4 acc[4];
#pragma unroll
    for (int c = 0; c < 4; ++c) acc[c] = make_float4(0.f, 0.f, 0.f, 0.f);

    // stream 8 rows per wave (rows wv*8 .. wv*8+7), prefetch next row
    {
        const float4* zr = (const float4*)(zbase + (size_t)(wv * 8) * NH);
        float4 z[4], zn[4];
#pragma unroll
        for (int c = 0; c < 4; ++c) z[c] = zr[c * 64 + lane];
#pragma unroll
        for (int r = 0; r < 8; ++r) {
            if (r < 7) {
                const float4* zr2 = (const float4*)(zbase + (size_t)(wv * 8 + r + 1) * NH);
#pragma unroll
                for (int c = 0; c < 4; ++c) zn[c] = zr2[c * 64 + lane];
            }
            float dot = 0.f;
#pragma unroll
            for (int c = 0; c < 4; ++c) dot += dot4f(z[c], qk[c]);
#pragma unroll
            for (int s = 1; s < 64; s <<= 1) dot += __shfl_xor(dot, s, 64);
            dot *= 0.03125f;                 // 1/sqrt(1024)
            float nm = fmaxf(m, dot);
            float scale = __expf(m - nm);    // first iter: exp(-inf)=0
            float p = __expf(dot - nm);
            d = d * scale + p;
#pragma unroll
            for (int c = 0; c < 4; ++c) {
                acc[c].x = acc[c].x * scale + p * z[c].x;
                acc[c].y = acc[c].y * scale + p * z[c].y;
                acc[c].z = acc[c].z * scale + p * z[c].z;
                acc[c].w = acc[c].w * scale + p * z[c].w;
            }
            m = nm;
#pragma unroll
            for (int c = 0; c < 4; ++c) z[c] = zn[c];
        }
    }

    // pairwise merge 8 -> 4 -> 2 -> 1 (upper half dumps, lower merges)
#pragma unroll
    for (int half = 4; half >= 1; half >>= 1) {
        if (wv >= half && wv < 2 * half) {
#pragma unroll
            for (int c = 0; c < 4; ++c) ((float4*)mbuf[wv - half])[c * 64 + lane] = acc[c];
            if (lane == 0) { md_lds[wv][0] = m; md_lds[wv][1] = d; }
        }
        __syncthreads();
        if (wv < half) {
            float mb = md_lds[wv + half][0], db = md_lds[wv + half][1];
            float nm = fmaxf(m, mb);
            float fa = __expf(m - nm), fb = __expf(mb - nm);
#pragma unroll
            for (int c = 0; c < 4; ++c) {
                float4 bv = ((const float4*)mbuf[wv])[c * 64 + lane];
                acc[c].x = acc[c].x * fa + bv.x * fb;
                acc[c].y = acc[c].y * fa + bv.y * fb;
                acc[c].z = acc[c].z * fa + bv.z * fb;
                acc[c].w = acc[c].w * fa + bv.w * fb;
            }
            d = d * fa + db * fb;
            m = nm;
        }
        __syncthreads();
    }

    // wave 0 holds the full H-wide result; fold retrieval weight and 1/d
    if (wv == 0) {
        float r_ = weights[b * NK + k] / d;
        float* pout = patt + ((size_t)b * NK + k) * NH;
#pragma unroll
        for (int c = 0; c < 4; ++c) {
            float4 o = acc[c];
            o.x *= r_; o.y *= r_; o.z *= r_; o.w *= r_;
            ((float4*)pout)[c * 64 + lane] = o;
        }
    }

    // F assembly by the last-arriving block for this b
    __threadfence();
    __syncthreads();
    if (t == 0)
        last_s = __hip_atomic_fetch_add(&g_cntb[b], 1, __ATOMIC_ACQ_REL,
                                        __HIP_MEMORY_SCOPE_AGENT);
    __syncthreads();
    if (last_s == NK - 1) {
        __threadfence();   // acquire side: other blocks' patt writes visible
        int j4 = t;        // 512 threads == 512 float4 == one F row
        float4 v;
        if (j4 < 256) {
            v = make_float4(0.f, 0.f, 0.f, 0.f);
#pragma unroll
            for (int kk = 0; kk < NK; ++kk) {
                float4 p = ((const float4*)patt)[((size_t)b * NK + kk) * 256 + j4];
                v.x += p.x; v.y += p.y; v.z += p.z; v.w += p.w;
            }
        } else {
            v = ((const float4*)(inputs + (size_t)b * NE))[j4 - 256];
        }
        ((float4*)F)[(size_t)b * 512 + j4] = v;
        if (t == 0)
            __hip_atomic_store(&g_cntb[b], 0, __ATOMIC_RELAXED,
                               __HIP_MEMORY_SCOPE_AGENT);   // self-reset
    }
}

// ---------------------------------------------------------------------------
// FINAL: out = F @ Wc^T + bc
// ---------------------------------------------------------------------------
__global__ __launch_bounds__(256)
void final_kernel(const float* __restrict__ F,
                  const float* __restrict__ Wc,
                  const float* __restrict__ bc,
                  float* __restrict__ out) {
    int wid = blockIdx.x * 4 + (threadIdx.x >> 6);  // 0..4095
    rowdot8<2048>(F, Wc, bc, out, wid);
}

// ---------------------------------------------------------------------------
extern "C" void kernel_launch(void* const* d_in, const int* in_sizes, int n_in,
                              void* d_out, int out_size, void* d_ws, size_t ws_size,
                              hipStream_t stream) {
    const float* inputs       = (const float*)d_in[0];
    const float* Wq           = (const float*)d_in[1];
    const float* bq           = (const float*)d_in[2];
    const float* Wk           = (const float*)d_in[3];
    // d_in[4] = bk: cancels in the l-softmax (constant over l)
    const float* Wc           = (const float*)d_in[5];
    const float* bc           = (const float*)d_in[6];
    const float* cache_keys   = (const float*)d_in[7];
    const float* cache_values = (const float*)d_in[8];
    float* out = (float*)d_out;

    float* ws      = (float*)d_ws;
    float* scores  = ws;                       // 4096
    float* query   = scores + 4096;            // 32768
    float* pqk     = query + 32768;            // 8*32*1024 = 262144
    float* patt    = pqk + 262144;             // 32*8*1024 = 262144
    float* F       = patt + 262144;            // 65536
    float* weights = F + 65536;                // 256
    int*   tidx    = (int*)(weights + 256);    // 256 ints
    (void)ws_size; (void)n_in; (void)in_sizes; (void)out_size;

    fat1_kernel<<<2048, 256, 0, stream>>>(cache_keys, inputs, Wq, bq, scores, query);
    fat2_kernel<<<1056, 256, 0, stream>>>(query, Wk, scores, pqk, tidx, weights);
    attn3_kernel<<<NB * NK, 512, 0, stream>>>(pqk, cache_values, tidx, weights,
                                              inputs, patt, F);
    final_kernel<<<1024, 256, 0, stream>>>(F, Wc, bc, out);
}

// Round 8
// 66.966 us; speedup vs baseline: 3.7736x; 1.7045x over previous
//
#include <hip/hip_runtime.h>
#include <math.h>

// Problem constants: B=32, E=1024, H=1024, N=128, L=64, K=8
#define NB 32
#define NE 1024
#define NH 1024
#define NN 128
#define NL 64
#define NK 8
#define GS 8   // g-chunks for qk partial sums

__device__ __forceinline__ float dot4f(float4 a, float4 b) {
    return a.x * b.x + a.y * b.y + a.z * b.z + a.w * b.w;
}

// ---------------------------------------------------------------------------
// rowdot8: one wave computes dot(W[o,:], A[b,:]) + bias[o] for 8 consecutive b
// ---------------------------------------------------------------------------
template <int D>
__device__ void rowdot8(const float* __restrict__ A, const float* __restrict__ W,
                        const float* __restrict__ bias, float* __restrict__ C,
                        int wid) {
    int lane = threadIdx.x & 63;
    int o  = wid >> 2;          // 0..1023
    int b0 = (wid & 3) * 8;     // batch group of 8
    const float4* Wr = (const float4*)(W + (size_t)o * D);
    const float4* Ar[8];
#pragma unroll
    for (int i = 0; i < 8; ++i) Ar[i] = (const float4*)(A + (size_t)(b0 + i) * D);
    float acc[8] = {0.f, 0.f, 0.f, 0.f, 0.f, 0.f, 0.f, 0.f};
#pragma unroll
    for (int c = 0; c < D / 256; ++c) {
        float4 w4 = Wr[c * 64 + lane];
#pragma unroll
        for (int i = 0; i < 8; ++i) acc[i] += dot4f(w4, Ar[i][c * 64 + lane]);
    }
#pragma unroll
    for (int s = 32; s; s >>= 1)
#pragma unroll
        for (int i = 0; i < 8; ++i) acc[i] += __shfl_down(acc[i], s, 64);
    if (lane == 0) {
        float bb = bias[o];
#pragma unroll
        for (int i = 0; i < 8; ++i) C[(size_t)(b0 + i) * NH + o] = acc[i] + bb;
    }
}

// ---------------------------------------------------------------------------
// FAT1: blocks [0,1024): scores[b,n] = cache_keys[b,n,:]·inputs[b,:]
//       blocks [1024,2048): query = inputs @ Wq^T + bq
// ---------------------------------------------------------------------------
__global__ __launch_bounds__(256)
void fat1_kernel(const float* __restrict__ cache_keys,
                 const float* __restrict__ inputs,
                 const float* __restrict__ Wq,
                 const float* __restrict__ bq,
                 float* __restrict__ scores,
                 float* __restrict__ query) {
    if (blockIdx.x < 1024) {
        int wid  = blockIdx.x * 4 + (threadIdx.x >> 6);   // 0..4095
        int lane = threadIdx.x & 63;
        int b = wid >> 7, n = wid & 127;
        const float4* ck = (const float4*)(cache_keys + ((size_t)b * NN + n) * NE);
        const float4* in = (const float4*)(inputs + (size_t)b * NE);
        float acc = 0.f;
#pragma unroll
        for (int c = 0; c < 4; ++c) acc += dot4f(ck[c * 64 + lane], in[c * 64 + lane]);
#pragma unroll
        for (int s = 32; s; s >>= 1) acc += __shfl_down(acc, s, 64);
        if (lane == 0) scores[b * NN + n] = acc;
    } else {
        int wid = (blockIdx.x - 1024) * 4 + (threadIdx.x >> 6);  // 0..4095
        rowdot8<1024>(inputs, Wq, bq, query, wid);
    }
}

// ---------------------------------------------------------------------------
// FAT2: blocks [0,1024): pqk partial GEMM tiled (16KB Wk per block);
//       blocks [1024,1056): per-batch top-8 + softmax.
// pqk[gs][b][h] = sum_{g in gs-chunk of 128} query[b,g] * Wk[g,h]
// (bk dropped: q·bk constant over l -> cancels in the l-softmax)
// ---------------------------------------------------------------------------
__global__ __launch_bounds__(256)
void fat2_kernel(const float* __restrict__ query,
                 const float* __restrict__ Wk,
                 const float* __restrict__ scores,
                 float* __restrict__ pqk,
                 int* __restrict__ top_idx,
                 float* __restrict__ weights) {
    __shared__ float qlds[128 * 8];     // [g_local][bj]  4KB
    __shared__ float red[8 * 32 * 8];   // [g_lane][h_local][bj] 8KB
    __shared__ float tv[NK];
    int t = threadIdx.x;
    if (blockIdx.x < 1024) {
        int gs = blockIdx.x & 7;
        int hs = (blockIdx.x >> 3) & 31;
        int bg = blockIdx.x >> 8;
        int b0 = bg * 8;
#pragma unroll
        for (int j = 0; j < 4; ++j) {
            int idx = t * 4 + j;
            int g = idx >> 3, bj = idx & 7;
            qlds[idx] = query[(size_t)(b0 + bj) * NH + gs * 128 + g];
        }
        __syncthreads();
        int h_local = t & 31, g_lane = t >> 5;
        int h = hs * 32 + h_local;
        float acc[8] = {0.f, 0.f, 0.f, 0.f, 0.f, 0.f, 0.f, 0.f};
#pragma unroll
        for (int i = 0; i < 16; ++i) {
            int g_local = g_lane * 16 + i;
            float w = Wk[(size_t)(gs * 128 + g_local) * NH + h];
            float4 q0 = *(const float4*)&qlds[g_local * 8];
            float4 q1 = *(const float4*)&qlds[g_local * 8 + 4];
            acc[0] += q0.x * w; acc[1] += q0.y * w; acc[2] += q0.z * w; acc[3] += q0.w * w;
            acc[4] += q1.x * w; acc[5] += q1.y * w; acc[6] += q1.z * w; acc[7] += q1.w * w;
        }
        *(float4*)&red[(g_lane * 32 + h_local) * 8]     = *(float4*)&acc[0];
        *(float4*)&red[(g_lane * 32 + h_local) * 8 + 4] = *(float4*)&acc[4];
        __syncthreads();
        int bj = t >> 5, hl = t & 31;
        float ssum = 0.f;
#pragma unroll
        for (int gl = 0; gl < 8; ++gl) ssum += red[(gl * 32 + hl) * 8 + bj];
        pqk[((size_t)gs * NB + b0 + bj) * NH + hs * 32 + hl] = ssum;
    } else {
        int b = blockIdx.x - 1024;
        if (t < 64) {
            float s0 = scores[b * NN + t];
            float s1 = scores[b * NN + 64 + t];
            for (int i = 0; i < NK; ++i) {
                float v = s0; int idx = t;
                if (s1 > v) { v = s1; idx = t + 64; }
#pragma unroll
                for (int s = 1; s < 64; s <<= 1) {
                    float ov = __shfl_xor(v, s, 64);
                    int   oi = __shfl_xor(idx, s, 64);
                    if (ov > v || (ov == v && oi < idx)) { v = ov; idx = oi; }
                }
                if (t == 0) { tv[i] = v; top_idx[b * NK + i] = idx; }
                if (idx == t)      s0 = -INFINITY;
                if (idx == t + 64) s1 = -INFINITY;
            }
        }
        __syncthreads();
        if (t < NK) {
            float e = __expf(tv[t] - tv[0]);   // tv[0] is the max
            float sum = e;
            sum += __shfl_xor(sum, 1, 64);
            sum += __shfl_xor(sum, 2, 64);
            sum += __shfl_xor(sum, 4, 64);
            weights[b * NK + t] = e / sum;
        }
    }
}

// ---------------------------------------------------------------------------
// ATTN: one 256-thread block per (b,k). Two passes over the zone.
//  phase1: 4 waves x 16 rows -> logits, 2 rows in flight (ILP on the
//          dot+reduce chains, which are otherwise ~200cy serial each).
//  phase2a: softmax over l (wave 0), retrieval weight folded in.
//  phase2b: per-thread float4 column over 64 rows, explicitly batch-unrolled
//           8 loads in flight (breaks the ~500cy L3-latency serialization).
// ---------------------------------------------------------------------------
__global__ __launch_bounds__(256)
void attn_kernel(const float* __restrict__ pqk,
                 const float* __restrict__ cache_values,
                 const int* __restrict__ top_idx,
                 const float* __restrict__ weights,
                 float* __restrict__ patt) {
    int b = blockIdx.x >> 3, k = blockIdx.x & 7;
    __shared__ float qk_lds[NH];    // 4KB
    __shared__ float logits[NL];
    __shared__ float coef[NL];
    int t = threadIdx.x;

    // qk[b,h] = sum_gs pqk[gs][b][h]  (256 threads x float4, coalesced)
    {
        float4 s = make_float4(0.f, 0.f, 0.f, 0.f);
#pragma unroll
        for (int gs = 0; gs < GS; ++gs) {
            float4 p = ((const float4*)pqk)[((size_t)gs * NB + b) * 256 + t];
            s.x += p.x; s.y += p.y; s.z += p.z; s.w += p.w;
        }
        ((float4*)qk_lds)[t] = s;
    }
    __syncthreads();

    int lane = t & 63, wv = t >> 6;
    int zi = top_idx[b * NK + k];
    const float* zbase = cache_values + (((size_t)b * NN + zi) * NL) * NH;

    // phase 1: wave wv owns rows [wv*16, wv*16+16), processed 2 at a time
    {
        float4 qk[4];
#pragma unroll
        for (int c = 0; c < 4; ++c) qk[c] = ((const float4*)qk_lds)[c * 64 + lane];
#pragma unroll
        for (int rp = 0; rp < 8; ++rp) {
            int l0 = wv * 16 + rp;
            int l1 = l0 + 8;
            const float4* zr0 = (const float4*)(zbase + (size_t)l0 * NH);
            const float4* zr1 = (const float4*)(zbase + (size_t)l1 * NH);
            float4 z0[4], z1[4];
#pragma unroll
            for (int c = 0; c < 4; ++c) { z0[c] = zr0[c * 64 + lane]; z1[c] = zr1[c * 64 + lane]; }
            float d0 = 0.f, d1 = 0.f;
#pragma unroll
            for (int c = 0; c < 4; ++c) { d0 += dot4f(z0[c], qk[c]); d1 += dot4f(z1[c], qk[c]); }
#pragma unroll
            for (int s = 32; s; s >>= 1) {
                d0 += __shfl_down(d0, s, 64);
                d1 += __shfl_down(d1, s, 64);
            }
            if (lane == 0) {
                logits[l0] = d0 * 0.03125f;   // 1/sqrt(1024)
                logits[l1] = d1 * 0.03125f;
            }
        }
    }
    __syncthreads();

    // phase 2a: softmax over l (wave 0), fold retrieval weight
    if (t < 64) {
        float v = logits[t];
        float m = v;
#pragma unroll
        for (int s = 1; s < 64; s <<= 1) m = fmaxf(m, __shfl_xor(m, s, 64));
        float e = __expf(v - m);
        float sum = e;
#pragma unroll
        for (int s = 1; s < 64; s <<= 1) sum += __shfl_xor(sum, s, 64);
        coef[t] = weights[b * NK + k] * e / sum;
    }
    __syncthreads();

    // phase 2b: thread t owns output float4 column t; 8 rows in flight
    {
        float4 acc = make_float4(0.f, 0.f, 0.f, 0.f);
#pragma unroll
        for (int lb = 0; lb < 8; ++lb) {
            float4 z[8];
#pragma unroll
            for (int j = 0; j < 8; ++j)
                z[j] = ((const float4*)(zbase + (size_t)(lb * 8 + j) * NH))[t];
#pragma unroll
            for (int j = 0; j < 8; ++j) {
                float c = coef[lb * 8 + j];
                acc.x += c * z[j].x; acc.y += c * z[j].y;
                acc.z += c * z[j].z; acc.w += c * z[j].w;
            }
        }
        ((float4*)patt)[((size_t)b * NK + k) * 256 + t] = acc;
    }
}

// ---------------------------------------------------------------------------
// buildF: F[b][0:1024] = sum_k patt[b][k][:], F[b][1024:2048] = inputs[b]
// ---------------------------------------------------------------------------
__global__ __launch_bounds__(256)
void buildF_kernel(const float* __restrict__ patt,
                   const float* __restrict__ inputs,
                   float* __restrict__ F) {
    int gid = blockIdx.x * 256 + threadIdx.x;   // 0..16383 float4s
    int b = gid >> 9, j4 = gid & 511;
    float4 v;
    if (j4 < 256) {
        v = make_float4(0.f, 0.f, 0.f, 0.f);
#pragma unroll
        for (int k = 0; k < NK; ++k) {
            float4 p = ((const float4*)patt)[((size_t)b * NK + k) * 256 + j4];
            v.x += p.x; v.y += p.y; v.z += p.z; v.w += p.w;
        }
    } else {
        v = ((const float4*)(inputs + (size_t)b * NE))[j4 - 256];
    }
    ((float4*)F)[(size_t)b * 512 + j4] = v;
}

// ---------------------------------------------------------------------------
// FINAL: out = F @ Wc^T + bc
// ---------------------------------------------------------------------------
__global__ __launch_bounds__(256)
void final_kernel(const float* __restrict__ F,
                  const float* __restrict__ Wc,
                  const float* __restrict__ bc,
                  float* __restrict__ out) {
    int wid = blockIdx.x * 4 + (threadIdx.x >> 6);  // 0..4095
    rowdot8<2048>(F, Wc, bc, out, wid);
}

// ---------------------------------------------------------------------------
extern "C" void kernel_launch(void* const* d_in, const int* in_sizes, int n_in,
                              void* d_out, int out_size, void* d_ws, size_t ws_size,
                              hipStream_t stream) {
    const float* inputs       = (const float*)d_in[0];
    const float* Wq           = (const float*)d_in[1];
    const float* bq           = (const float*)d_in[2];
    const float* Wk           = (const float*)d_in[3];
    // d_in[4] = bk: cancels in the l-softmax (constant over l)
    const float* Wc           = (const float*)d_in[5];
    const float* bc           = (const float*)d_in[6];
    const float* cache_keys   = (const float*)d_in[7];
    const float* cache_values = (const float*)d_in[8];
    float* out = (float*)d_out;

    float* ws      = (float*)d_ws;
    float* scores  = ws;                       // 4096
    float* query   = scores + 4096;            // 32768
    float* pqk     = query + 32768;            // 8*32*1024 = 262144
    float* patt    = pqk + 262144;             // 32*8*1024 = 262144
    float* F       = patt + 262144;            // 65536
    float* weights = F + 65536;                // 256
    int*   tidx    = (int*)(weights + 256);    // 256 ints
    (void)ws_size; (void)n_in; (void)in_sizes; (void)out_size;

    fat1_kernel<<<2048, 256, 0, stream>>>(cache_keys, inputs, Wq, bq, scores, query);
    fat2_kernel<<<1056, 256, 0, stream>>>(query, Wk, scores, pqk, tidx, weights);
    attn_kernel<<<NB * NK, 256, 0, stream>>>(pqk, cache_values, tidx, weights, patt);
    buildF_kernel<<<64, 256, 0, stream>>>(patt, inputs, F);
    final_kernel<<<1024, 256, 0, stream>>>(F, Wc, bc, out);
}